// Round 1
// baseline (6405.004 us; speedup 1.0000x reference)
//
#include <hip/hip_runtime.h>
#include <math.h>

#define N_ENT   100000
#define N_USR   50000
#define N_ITM   30000
#define DD      64
#define N_REL   16
#define N_CLS   4
#define N_EDGES 1500000
#define NNZ_IM  1000000
#define NNZ_ICM 1000000
#define TMP_    0.2f

// ---------- helpers ----------
__device__ __forceinline__ float wave_sum(float v) {
    #pragma unroll
    for (int off = 32; off; off >>= 1) v += __shfl_xor(v, off, 64);
    return v;
}

// ---------- rsum = relation_emb.sum(0) : 64 floats ----------
__global__ void rsum_kernel(const float* __restrict__ rel, float* __restrict__ rsum) {
    int l = threadIdx.x;           // 0..63
    float s = 0.f;
    #pragma unroll
    for (int r = 0; r < N_REL; ++r) s += rel[r * DD + l];
    rsum[l] = s;
}

// ---------- att[i][r] = softmax_r( e[i] . rel[r] ) : wave per entity ----------
__global__ void att_kernel(const float* __restrict__ e, const float* __restrict__ rel,
                           float* __restrict__ att, int n) {
    int wave = (blockIdx.x * blockDim.x + threadIdx.x) >> 6;
    int lane = threadIdx.x & 63;
    if (wave >= n) return;
    float x = e[(long long)wave * DD + lane];
    float d[N_REL];
    #pragma unroll
    for (int r = 0; r < N_REL; ++r) {
        float p = x * rel[r * DD + lane];
        d[r] = wave_sum(p);                 // all lanes hold the dot
    }
    float m = d[0];
    #pragma unroll
    for (int r = 1; r < N_REL; ++r) m = fmaxf(m, d[r]);
    float s = 0.f;
    #pragma unroll
    for (int r = 0; r < N_REL; ++r) { d[r] = expf(d[r] - m); s += d[r]; }
    float inv = 1.f / s;
    if (lane < N_REL) {
        float v = d[0];
        #pragma unroll
        for (int r = 1; r < N_REL; ++r) v = (lane == r) ? d[r] : v;
        att[(long long)wave * N_REL + lane] = v * inv;
    }
}

// ---------- ucls[u][c] = softmax_c( u . w[c] ) : wave per user ----------
__global__ void ucls_kernel(const float* __restrict__ u, const float* __restrict__ w,
                            float* __restrict__ ucls, int n) {
    int wave = (blockIdx.x * blockDim.x + threadIdx.x) >> 6;
    int lane = threadIdx.x & 63;
    if (wave >= n) return;
    float x = u[(long long)wave * DD + lane];
    float d[N_CLS];
    #pragma unroll
    for (int c = 0; c < N_CLS; ++c) {
        float p = x * w[c * DD + lane];
        d[c] = wave_sum(p);
    }
    float m = fmaxf(fmaxf(d[0], d[1]), fmaxf(d[2], d[3]));
    float s = 0.f;
    #pragma unroll
    for (int c = 0; c < N_CLS; ++c) { d[c] = expf(d[c] - m); s += d[c]; }
    float inv = 1.f / s;
    if (lane < N_CLS) {
        float v = d[0];
        #pragma unroll
        for (int c = 1; c < N_CLS; ++c) v = (lane == c) ? d[c] : v;
        ucls[(long long)wave * N_CLS + lane] = v * inv;
    }
}

// ---------- entity_agg[head] += e[tail] * rel[etype] * (att[head,etype]*imp) ----------
// 16 lanes per edge, float4 per lane.
__global__ void edge_kernel(const float* __restrict__ e, const float* __restrict__ rel,
                            const float* __restrict__ att, const float* __restrict__ imp,
                            const int* __restrict__ head, const int* __restrict__ tail,
                            const int* __restrict__ etype, float* __restrict__ agg) {
    long long t = (long long)blockIdx.x * blockDim.x + threadIdx.x;
    int eidx = (int)(t >> 4);
    int c = (int)(t & 15);
    if (eidx >= N_EDGES) return;
    int lane = threadIdx.x & 63;
    int base = lane & 48;                       // lane with c==0 in this 16-group
    int h = 0, tl = 0, et = 0; float w = 0.f;
    if (c == 0) {
        h = head[eidx]; tl = tail[eidx]; et = etype[eidx];
        w = att[(long long)h * N_REL + et] * imp[eidx];
    }
    h  = __shfl(h,  base, 64);
    tl = __shfl(tl, base, 64);
    et = __shfl(et, base, 64);
    w  = __shfl(w,  base, 64);
    float4 ev = *(const float4*)(e   + (long long)tl * DD + c * 4);
    float4 rv = *(const float4*)(rel + (long long)et * DD + c * 4);
    float* dst = agg + (long long)h * DD + c * 4;
    atomicAdd(dst + 0, ev.x * rv.x * w);
    atomicAdd(dst + 1, ev.y * rv.y * w);
    atomicAdd(dst + 2, ev.z * rv.z * w);
    atomicAdd(dst + 3, ev.w * rv.w * w);
}

// ---------- user_agg[row] += val * e[col] ----------
__global__ void im_kernel(const float* __restrict__ e, const float* __restrict__ vals,
                          const int* __restrict__ rows, const int* __restrict__ cols,
                          float* __restrict__ agg) {
    long long t = (long long)blockIdx.x * blockDim.x + threadIdx.x;
    int k = (int)(t >> 4);
    int c = (int)(t & 15);
    if (k >= NNZ_IM) return;
    int lane = threadIdx.x & 63;
    int base = lane & 48;
    int r = 0, col = 0; float v = 0.f;
    if (c == 0) { r = rows[k]; col = cols[k]; v = vals[k]; }
    r   = __shfl(r,   base, 64);
    col = __shfl(col, base, 64);
    v   = __shfl(v,   base, 64);
    float4 ev = *(const float4*)(e + (long long)col * DD + c * 4);
    float* dst = agg + (long long)r * DD + c * 4;
    atomicAdd(dst + 0, ev.x * v);
    atomicAdd(dst + 1, ev.y * v);
    atomicAdd(dst + 2, ev.z * v);
    atomicAdd(dst + 3, ev.w * v);
}

// ---------- user_agg[row] += icm_val * ucls[row,cls] * (e[col] .* rsum) (fused einsum) ----------
__global__ void icm_kernel(const float* __restrict__ e, const float* __restrict__ vals,
                           const int* __restrict__ rows, const int* __restrict__ cols,
                           const int* __restrict__ cls, const float* __restrict__ ucls,
                           const float* __restrict__ rsum, float* __restrict__ agg) {
    long long t = (long long)blockIdx.x * blockDim.x + threadIdx.x;
    int k = (int)(t >> 4);
    int c = (int)(t & 15);
    if (k >= NNZ_ICM) return;
    int lane = threadIdx.x & 63;
    int base = lane & 48;
    int r = 0, col = 0; float w = 0.f;
    if (c == 0) {
        r = rows[k]; col = cols[k];
        int cl = cls[k];
        w = vals[k] * ucls[(long long)r * N_CLS + cl];
    }
    r   = __shfl(r,   base, 64);
    col = __shfl(col, base, 64);
    w   = __shfl(w,   base, 64);
    float4 ev = *(const float4*)(e    + (long long)col * DD + c * 4);
    float4 rs = *(const float4*)(rsum + c * 4);
    float* dst = agg + (long long)r * DD + c * 4;
    atomicAdd(dst + 0, ev.x * rs.x * w);
    atomicAdd(dst + 1, ev.y * rs.y * w);
    atomicAdd(dst + 2, ev.z * rs.z * w);
    atomicAdd(dst + 3, ev.w * rs.w * w);
}

// ---------- e_new = l2n(agg); cur = e_new; res += e_new : wave per row ----------
__global__ void norm_kernel(const float* __restrict__ agg, float* __restrict__ cur,
                            float* __restrict__ res, int n) {
    int wave = (blockIdx.x * blockDim.x + threadIdx.x) >> 6;
    int lane = threadIdx.x & 63;
    if (wave >= n) return;
    long long idx = (long long)wave * DD + lane;
    float x = agg[idx];
    float ss = wave_sum(x * x);
    float nrm = fmaxf(sqrtf(ss), 1e-12f);
    float y = x / nrm;
    cur[idx] = y;
    res[idx] += y;
}

// ---------- cor_loss (4x16, trivial) ----------
__global__ void cor_kernel(const float* __restrict__ dwatt, float* __restrict__ out) {
    if (threadIdx.x != 0 || blockIdx.x != 0) return;
    float nt[4][16];
    #pragma unroll
    for (int i = 0; i < 4; ++i) {
        float ss = 0.f;
        #pragma unroll
        for (int j = 0; j < 16; ++j) { float v = dwatt[i * 16 + j]; ss += v * v; }
        float nrm = fmaxf(sqrtf(ss), 1e-12f);
        #pragma unroll
        for (int j = 0; j < 16; ++j) nt[i][j] = dwatt[i * 16 + j] / nrm;
    }
    float loss = 0.f;
    #pragma unroll
    for (int i = 0; i < 4; ++i) {
        float rowsum = 0.f, diag = 0.f;
        #pragma unroll
        for (int j = 0; j < 4; ++j) {
            float d = 0.f;
            #pragma unroll
            for (int k = 0; k < 16; ++k) d += nt[i][k] * nt[j][k];
            float s = expf(d / TMP_);
            rowsum += s;
            if (i == j) diag = s;
        }
        loss -= logf(diag / rowsum);
    }
    out[0] = loss;
}

extern "C" void kernel_launch(void* const* d_in, const int* in_sizes, int n_in,
                              void* d_out, int out_size, void* d_ws, size_t ws_size,
                              hipStream_t stream) {
    const float* user_emb   = (const float*)d_in[0];
    const float* entity_emb = (const float*)d_in[1];
    // d_in[2] latent_emb: unused by reference
    const float* rel        = (const float*)d_in[3];
    const float* dwatt      = (const float*)d_in[4];
    const float* uclsw      = (const float*)d_in[5];
    const float* edge_imp   = (const float*)d_in[6];
    const float* im_vals    = (const float*)d_in[7];
    const float* icm_vals   = (const float*)d_in[8];
    const int*   edge_index = (const int*)d_in[9];
    const int*   edge_type  = (const int*)d_in[10];
    const int*   im_rows    = (const int*)d_in[11];
    const int*   im_cols    = (const int*)d_in[12];
    const int*   icm_cls    = (const int*)d_in[13];
    const int*   icm_rows   = (const int*)d_in[14];
    const int*   icm_cols   = (const int*)d_in[15];

    float* out     = (float*)d_out;
    float* ent_res = out;
    float* usr_res = out + (long long)N_ENT * DD;
    float* cor     = out + (long long)(N_ENT + N_USR) * DD;

    float* ws    = (float*)d_ws;
    float* e_cur = ws;                          // 6.4M
    float* u_cur = e_cur + (long long)N_ENT * DD;  // 3.2M
    float* e_agg = u_cur + (long long)N_USR * DD;  // 6.4M
    float* u_agg = e_agg + (long long)N_ENT * DD;  // 3.2M
    float* att   = u_agg + (long long)N_USR * DD;  // 1.6M
    float* ucls  = att + (long long)N_ENT * N_REL; // 0.2M
    float* rsum  = ucls + (long long)N_USR * N_CLS;

    hipMemcpyAsync(e_cur,   entity_emb, sizeof(float) * N_ENT * DD, hipMemcpyDeviceToDevice, stream);
    hipMemcpyAsync(u_cur,   user_emb,   sizeof(float) * N_USR * DD, hipMemcpyDeviceToDevice, stream);
    hipMemcpyAsync(ent_res, entity_emb, sizeof(float) * N_ENT * DD, hipMemcpyDeviceToDevice, stream);
    hipMemcpyAsync(usr_res, user_emb,   sizeof(float) * N_USR * DD, hipMemcpyDeviceToDevice, stream);
    rsum_kernel<<<1, 64, 0, stream>>>(rel, rsum);

    const int BLK = 256;
    for (int hop = 0; hop < 2; ++hop) {
        hipMemsetAsync(e_agg, 0, sizeof(float) * N_ENT * DD, stream);
        hipMemsetAsync(u_agg, 0, sizeof(float) * N_USR * DD, stream);

        att_kernel <<<(N_ENT * 64 + BLK - 1) / BLK, BLK, 0, stream>>>(e_cur, rel, att, N_ENT);
        ucls_kernel<<<(N_USR * 64 + BLK - 1) / BLK, BLK, 0, stream>>>(u_cur, uclsw, ucls, N_USR);

        long long et = (long long)N_EDGES * 16;
        edge_kernel<<<(int)((et + BLK - 1) / BLK), BLK, 0, stream>>>(
            e_cur, rel, att, edge_imp, edge_index, edge_index + N_EDGES, edge_type, e_agg);

        long long imt = (long long)NNZ_IM * 16;
        im_kernel<<<(int)((imt + BLK - 1) / BLK), BLK, 0, stream>>>(
            e_cur, im_vals, im_rows, im_cols, u_agg);

        long long icmt = (long long)NNZ_ICM * 16;
        icm_kernel<<<(int)((icmt + BLK - 1) / BLK), BLK, 0, stream>>>(
            e_cur, icm_vals, icm_rows, icm_cols, icm_cls, ucls, rsum, u_agg);

        norm_kernel<<<(N_ENT * 64 + BLK - 1) / BLK, BLK, 0, stream>>>(e_agg, e_cur, ent_res, N_ENT);
        norm_kernel<<<(N_USR * 64 + BLK - 1) / BLK, BLK, 0, stream>>>(u_agg, u_cur, usr_res, N_USR);
    }
    cor_kernel<<<1, 1, 0, stream>>>(dwatt, cor);
}

// Round 2
// 1798.248 us; speedup vs baseline: 3.5618x; 3.5618x over previous
//
#include <hip/hip_runtime.h>
#include <math.h>

#define N_ENT   100000
#define N_USR   50000
#define N_ITM   30000
#define DD      64
#define N_REL   16
#define N_CLS   4
#define N_EDGES 1500000
#define NNZ_IM  1000000
#define NNZ_ICM 1000000
#define TMP_    0.2f

// ---------- helpers ----------
__device__ __forceinline__ float wave_sum(float v) {
    #pragma unroll
    for (int off = 32; off; off >>= 1) v += __shfl_xor(v, off, 64);
    return v;
}

// ---------- rsum = relation_emb.sum(0) : 64 floats ----------
__global__ void rsum_kernel(const float* __restrict__ rel, float* __restrict__ rsum) {
    int l = threadIdx.x;
    float s = 0.f;
    #pragma unroll
    for (int r = 0; r < N_REL; ++r) s += rel[r * DD + l];
    rsum[l] = s;
}

// ---------- CSR build: histogram ----------
__global__ void hist_kernel(const int* __restrict__ idx, int* __restrict__ deg, int n) {
    int i = blockIdx.x * blockDim.x + threadIdx.x;
    if (i < n) atomicAdd(&deg[idx[i]], 1);
}

// ---------- CSR build: 3 exclusive scans, one block each ----------
__device__ void block_exscan(const int* __restrict__ deg, int* __restrict__ off, int n) {
    __shared__ int wsum[16];
    __shared__ int s_carry;
    int tid = threadIdx.x;
    int lane = tid & 63, wid = tid >> 6;
    if (tid == 0) s_carry = 0;
    __syncthreads();
    for (int base = 0; base < n; base += 1024) {
        int i = base + tid;
        int v = (i < n) ? deg[i] : 0;
        int inc = v;
        #pragma unroll
        for (int d = 1; d < 64; d <<= 1) {
            int t = __shfl_up(inc, d, 64);
            if (lane >= d) inc += t;
        }
        if (lane == 63) wsum[wid] = inc;
        __syncthreads();
        int wpre = 0;
        #pragma unroll
        for (int w = 0; w < 16; ++w) wpre += (w < wid) ? wsum[w] : 0;
        int carry = s_carry;
        if (i < n) off[i] = carry + wpre + inc - v;
        __syncthreads();
        if (tid == 1023) s_carry = carry + wpre + inc;   // carry + chunk total
        __syncthreads();
    }
    if (tid == 0) off[n] = s_carry;
}

__global__ void scan3_kernel(const int* d0, int* o0, int n0,
                             const int* d1, int* o1, int n1,
                             const int* d2, int* o2, int n2) {
    if (blockIdx.x == 0)      block_exscan(d0, o0, n0);
    else if (blockIdx.x == 1) block_exscan(d1, o1, n1);
    else                      block_exscan(d2, o2, n2);
}

// ---------- CSR build: scatter edge ids ----------
__global__ void scatter_kernel(const int* __restrict__ idx, int* __restrict__ cur,
                               int* __restrict__ ids, int n) {
    int i = blockIdx.x * blockDim.x + threadIdx.x;
    if (i < n) { int p = atomicAdd(&cur[idx[i]], 1); ids[p] = i; }
}

// ---------- per-hop entity update: wave per entity ----------
// inline relation-softmax + CSR gather + l2norm + residual accumulate
__global__ void __launch_bounds__(256) ent_hop_kernel(
    const float* __restrict__ e_cur, float* __restrict__ e_next,
    const float* __restrict__ rel, const float* __restrict__ imp,
    const int* __restrict__ tail, const int* __restrict__ etype,
    const int* __restrict__ ids, const int* __restrict__ off,
    float* __restrict__ res)
{
    __shared__ float att_lds[4 * N_REL];
    int gw = (blockIdx.x * blockDim.x + threadIdx.x) >> 6;
    int lane = threadIdx.x & 63;
    int wid = threadIdx.x >> 6;
    if (gw >= N_ENT) return;
    long long o = (long long)gw * DD + lane;
    float x = e_cur[o];
    float d[N_REL];
    #pragma unroll
    for (int r = 0; r < N_REL; ++r) d[r] = wave_sum(x * rel[r * DD + lane]);
    float m = d[0];
    #pragma unroll
    for (int r = 1; r < N_REL; ++r) m = fmaxf(m, d[r]);
    float ssum = 0.f;
    #pragma unroll
    for (int r = 0; r < N_REL; ++r) { d[r] = expf(d[r] - m); ssum += d[r]; }
    float inv = 1.f / ssum;
    float v = d[0];
    #pragma unroll
    for (int r = 1; r < N_REL; ++r) v = (lane == r) ? d[r] : v;
    if (lane < N_REL) att_lds[wid * N_REL + lane] = v * inv;   // same-wave read: no barrier

    int j0 = off[gw], j1 = off[gw + 1];
    float acc = 0.f;
    for (int j = j0; j < j1; ++j) {
        int eid = ids[j];
        int tl  = tail[eid];
        int et  = etype[eid];
        float w = att_lds[wid * N_REL + et] * imp[eid];
        acc += e_cur[(long long)tl * DD + lane] * rel[et * DD + lane] * w;
    }
    float nrm = fmaxf(sqrtf(wave_sum(acc * acc)), 1e-12f);
    float y = acc / nrm;
    e_next[o] = y;
    res[o] += y;
}

// ---------- per-hop user update: wave per user ----------
// inline cluster-softmax + im gather + fused icm/einsum gather + l2norm + residual
__global__ void __launch_bounds__(256) usr_hop_kernel(
    float* __restrict__ u, const float* __restrict__ e_cur,
    const float* __restrict__ uclsw,
    const float* __restrict__ im_vals, const int* __restrict__ im_cols,
    const int* __restrict__ im_ids, const int* __restrict__ im_off,
    const float* __restrict__ icm_vals, const int* __restrict__ icm_cols,
    const int* __restrict__ icm_cls,
    const int* __restrict__ icm_ids, const int* __restrict__ icm_off,
    const float* __restrict__ rsum, float* __restrict__ res)
{
    __shared__ float cls_lds[4 * N_CLS];
    int gw = (blockIdx.x * blockDim.x + threadIdx.x) >> 6;
    int lane = threadIdx.x & 63;
    int wid = threadIdx.x >> 6;
    if (gw >= N_USR) return;
    long long o = (long long)gw * DD + lane;
    float x = u[o];
    float d[N_CLS];
    #pragma unroll
    for (int c = 0; c < N_CLS; ++c) d[c] = wave_sum(x * uclsw[c * DD + lane]);
    float m = fmaxf(fmaxf(d[0], d[1]), fmaxf(d[2], d[3]));
    float ssum = 0.f;
    #pragma unroll
    for (int c = 0; c < N_CLS; ++c) { d[c] = expf(d[c] - m); ssum += d[c]; }
    float inv = 1.f / ssum;
    float v = d[0];
    #pragma unroll
    for (int c = 1; c < N_CLS; ++c) v = (lane == c) ? d[c] : v;
    if (lane < N_CLS) cls_lds[wid * N_CLS + lane] = v * inv;

    float acc = 0.f;
    {
        int j0 = im_off[gw], j1 = im_off[gw + 1];
        for (int j = j0; j < j1; ++j) {
            int k = im_ids[j];
            acc += im_vals[k] * e_cur[(long long)im_cols[k] * DD + lane];
        }
    }
    float acc2 = 0.f;
    {
        int j0 = icm_off[gw], j1 = icm_off[gw + 1];
        for (int j = j0; j < j1; ++j) {
            int k = icm_ids[j];
            float w = icm_vals[k] * cls_lds[wid * N_CLS + icm_cls[k]];
            acc2 += w * e_cur[(long long)icm_cols[k] * DD + lane];
        }
    }
    acc += acc2 * rsum[lane];

    float nrm = fmaxf(sqrtf(wave_sum(acc * acc)), 1e-12f);
    float y = acc / nrm;
    u[o] = y;          // in-place: users only read their own row
    res[o] += y;
}

// ---------- cor_loss (4x16, trivial) ----------
__global__ void cor_kernel(const float* __restrict__ dwatt, float* __restrict__ out) {
    if (threadIdx.x != 0 || blockIdx.x != 0) return;
    float nt[4][16];
    #pragma unroll
    for (int i = 0; i < 4; ++i) {
        float ss = 0.f;
        #pragma unroll
        for (int j = 0; j < 16; ++j) { float v = dwatt[i * 16 + j]; ss += v * v; }
        float nrm = fmaxf(sqrtf(ss), 1e-12f);
        #pragma unroll
        for (int j = 0; j < 16; ++j) nt[i][j] = dwatt[i * 16 + j] / nrm;
    }
    float loss = 0.f;
    #pragma unroll
    for (int i = 0; i < 4; ++i) {
        float rowsum = 0.f, diag = 0.f;
        #pragma unroll
        for (int j = 0; j < 4; ++j) {
            float dd = 0.f;
            #pragma unroll
            for (int k = 0; k < 16; ++k) dd += nt[i][k] * nt[j][k];
            float s = expf(dd / TMP_);
            rowsum += s;
            if (i == j) diag = s;
        }
        loss -= logf(diag / rowsum);
    }
    out[0] = loss;
}

extern "C" void kernel_launch(void* const* d_in, const int* in_sizes, int n_in,
                              void* d_out, int out_size, void* d_ws, size_t ws_size,
                              hipStream_t stream) {
    const float* user_emb   = (const float*)d_in[0];
    const float* entity_emb = (const float*)d_in[1];
    const float* rel        = (const float*)d_in[3];
    const float* dwatt      = (const float*)d_in[4];
    const float* uclsw      = (const float*)d_in[5];
    const float* edge_imp   = (const float*)d_in[6];
    const float* im_vals    = (const float*)d_in[7];
    const float* icm_vals   = (const float*)d_in[8];
    const int*   edge_index = (const int*)d_in[9];
    const int*   edge_type  = (const int*)d_in[10];
    const int*   im_rows    = (const int*)d_in[11];
    const int*   im_cols    = (const int*)d_in[12];
    const int*   icm_cls    = (const int*)d_in[13];
    const int*   icm_rows   = (const int*)d_in[14];
    const int*   icm_cols   = (const int*)d_in[15];

    const int* head  = edge_index;
    const int* tailp = edge_index + N_EDGES;

    float* out     = (float*)d_out;
    float* ent_res = out;
    float* usr_res = out + (long long)N_ENT * DD;
    float* cor     = out + (long long)(N_ENT + N_USR) * DD;

    // workspace: floats then ints  (~80 MB total)
    float* ws   = (float*)d_ws;
    float* e0   = ws;                               // 6.4M f
    float* e1   = e0 + (size_t)N_ENT * DD;          // 6.4M f
    float* ub   = e1 + (size_t)N_ENT * DD;          // 3.2M f
    float* rsum = ub + (size_t)N_USR * DD;          // 64 f
    int* ip    = (int*)(rsum + DD);
    int* e_off = ip;  ip += N_ENT + 1;
    int* e_cu  = ip;  ip += N_ENT;
    int* e_ids = ip;  ip += N_EDGES;
    int* i_off = ip;  ip += N_USR + 1;
    int* i_cu  = ip;  ip += N_USR;
    int* i_ids = ip;  ip += NNZ_IM;
    int* c_off = ip;  ip += N_USR + 1;
    int* c_cu  = ip;  ip += N_USR;
    int* c_ids = ip;  ip += NNZ_ICM;

    const int BLK = 256;

    // ---- build 3 CSRs (index sets are call-invariant within a launch) ----
    hipMemsetAsync(e_cu, 0, sizeof(int) * N_ENT, stream);
    hipMemsetAsync(i_cu, 0, sizeof(int) * N_USR, stream);
    hipMemsetAsync(c_cu, 0, sizeof(int) * N_USR, stream);
    hist_kernel<<<(N_EDGES + BLK - 1) / BLK, BLK, 0, stream>>>(head, e_cu, N_EDGES);
    hist_kernel<<<(NNZ_IM + BLK - 1) / BLK, BLK, 0, stream>>>(im_rows, i_cu, NNZ_IM);
    hist_kernel<<<(NNZ_ICM + BLK - 1) / BLK, BLK, 0, stream>>>(icm_rows, c_cu, NNZ_ICM);
    scan3_kernel<<<3, 1024, 0, stream>>>(e_cu, e_off, N_ENT, i_cu, i_off, N_USR, c_cu, c_off, N_USR);
    hipMemcpyAsync(e_cu, e_off, sizeof(int) * N_ENT, hipMemcpyDeviceToDevice, stream);
    hipMemcpyAsync(i_cu, i_off, sizeof(int) * N_USR, hipMemcpyDeviceToDevice, stream);
    hipMemcpyAsync(c_cu, c_off, sizeof(int) * N_USR, hipMemcpyDeviceToDevice, stream);
    scatter_kernel<<<(N_EDGES + BLK - 1) / BLK, BLK, 0, stream>>>(head, e_cu, e_ids, N_EDGES);
    scatter_kernel<<<(NNZ_IM + BLK - 1) / BLK, BLK, 0, stream>>>(im_rows, i_cu, i_ids, NNZ_IM);
    scatter_kernel<<<(NNZ_ICM + BLK - 1) / BLK, BLK, 0, stream>>>(icm_rows, c_cu, c_ids, NNZ_ICM);

    // ---- init state ----
    rsum_kernel<<<1, 64, 0, stream>>>(rel, rsum);
    hipMemcpyAsync(e0, entity_emb, sizeof(float) * N_ENT * DD, hipMemcpyDeviceToDevice, stream);
    hipMemcpyAsync(ub, user_emb, sizeof(float) * N_USR * DD, hipMemcpyDeviceToDevice, stream);
    hipMemcpyAsync(ent_res, entity_emb, sizeof(float) * N_ENT * DD, hipMemcpyDeviceToDevice, stream);
    hipMemcpyAsync(usr_res, user_emb, sizeof(float) * N_USR * DD, hipMemcpyDeviceToDevice, stream);

    // ---- 2 hops, double-buffered entities, in-place users ----
    for (int hop = 0; hop < 2; ++hop) {
        const float* ec = hop ? e1 : e0;
        float*       en = hop ? e0 : e1;
        ent_hop_kernel<<<(N_ENT * 64 + BLK - 1) / BLK, BLK, 0, stream>>>(
            ec, en, rel, edge_imp, tailp, edge_type, e_ids, e_off, ent_res);
        usr_hop_kernel<<<(N_USR * 64 + BLK - 1) / BLK, BLK, 0, stream>>>(
            ub, ec, uclsw, im_vals, im_cols, i_ids, i_off,
            icm_vals, icm_cols, icm_cls, c_ids, c_off, rsum, usr_res);
    }
    cor_kernel<<<1, 1, 0, stream>>>(dwatt, cor);
}

// Round 3
// 943.890 us; speedup vs baseline: 6.7858x; 1.9051x over previous
//
#include <hip/hip_runtime.h>
#include <math.h>

#define N_ENT   100000
#define N_USR   50000
#define DD      64
#define N_REL   16
#define N_CLS   4
#define N_EDGES 1500000
#define NNZ_IM  1000000
#define NNZ_ICM 1000000
#define TMP_    0.2f
#define ENT_BLKS (N_ENT / 4)
#define USR_BLKS (N_USR / 4)

// ---------- helpers ----------
__device__ __forceinline__ float wave_sum(float v) {
    #pragma unroll
    for (int off = 32; off; off >>= 1) v += __shfl_xor(v, off, 64);
    return v;
}

// ---------- rsum = relation_emb.sum(0) ----------
__global__ void rsum_kernel(const float* __restrict__ rel, float* __restrict__ rsum) {
    int l = threadIdx.x;
    float s = 0.f;
    #pragma unroll
    for (int r = 0; r < N_REL; ++r) s += rel[r * DD + l];
    rsum[l] = s;
}

// ---------- CSR build ----------
__global__ void hist_kernel(const int* __restrict__ idx, int* __restrict__ deg, int n) {
    int i = blockIdx.x * blockDim.x + threadIdx.x;
    if (i < n) atomicAdd(&deg[idx[i]], 1);
}

// wave-aggregated segment allocator: cnt[i] = segment start (arbitrary global order)
__global__ void assign_kernel(const int* __restrict__ deg, int* __restrict__ cnt,
                              int* __restrict__ gc, int n) {
    int i = blockIdx.x * blockDim.x + threadIdx.x;
    int lane = threadIdx.x & 63;
    int d = (i < n) ? deg[i] : 0;
    int incl = d;
    #pragma unroll
    for (int off = 1; off < 64; off <<= 1) {
        int t = __shfl_up(incl, off, 64);
        if (lane >= off) incl += t;
    }
    int base = 0;
    if (lane == 63) base = atomicAdd(gc, incl);
    base = __shfl(base, 63, 64);
    if (i < n) cnt[i] = base + incl - d;
}

__global__ void scatter_edge_kernel(const int* __restrict__ head, const int* __restrict__ tail,
                                    const int* __restrict__ etype, const float* __restrict__ imp,
                                    int* __restrict__ cnt, int2* __restrict__ pack, int n) {
    int i = blockIdx.x * blockDim.x + threadIdx.x;
    if (i < n) {
        int p = atomicAdd(&cnt[head[i]], 1);
        pack[p] = make_int2(tail[i] | (etype[i] << 17), __float_as_int(imp[i]));
    }
}
__global__ void scatter_im_kernel(const int* __restrict__ rows, const int* __restrict__ cols,
                                  const float* __restrict__ vals,
                                  int* __restrict__ cnt, int2* __restrict__ pack, int n) {
    int i = blockIdx.x * blockDim.x + threadIdx.x;
    if (i < n) {
        int p = atomicAdd(&cnt[rows[i]], 1);
        pack[p] = make_int2(cols[i], __float_as_int(vals[i]));
    }
}
__global__ void scatter_icm_kernel(const int* __restrict__ rows, const int* __restrict__ cols,
                                   const int* __restrict__ cls, const float* __restrict__ vals,
                                   int* __restrict__ cnt, int2* __restrict__ pack, int n) {
    int i = blockIdx.x * blockDim.x + threadIdx.x;
    if (i < n) {
        int p = atomicAdd(&cnt[rows[i]], 1);
        pack[p] = make_int2(cols[i] | (cls[i] << 15), __float_as_int(vals[i]));
    }
}

// ---------- fused per-hop kernel: entity blocks then user blocks ----------
// gather phase: 16-lane groups, float4/lane -> 4 independent CSR slots in flight per wave
__global__ void __launch_bounds__(256) hop_kernel(
    const float* __restrict__ e_src, float* __restrict__ e_next,
    float* __restrict__ ub,
    const float* __restrict__ rel, const float* __restrict__ uclsw,
    const float* __restrict__ rsum,
    const int* __restrict__ e_deg, const int* __restrict__ e_end, const int2* __restrict__ epack,
    const int* __restrict__ i_deg, const int* __restrict__ i_end, const int2* __restrict__ impack,
    const int* __restrict__ c_deg, const int* __restrict__ c_end, const int2* __restrict__ icpack,
    float* __restrict__ ent_res, float* __restrict__ usr_res, int store_next)
{
    __shared__ float smax[4 * N_REL];
    const int lane = threadIdx.x & 63;
    const int wid  = threadIdx.x >> 6;
    const int g = lane >> 4;
    const int s = lane & 15;

    if (blockIdx.x < ENT_BLKS) {
        const int gw = blockIdx.x * 4 + wid;
        const long long o = (long long)gw * DD + lane;
        const float x = e_src[o];
        // relation softmax (lane-per-element layout)
        float d[N_REL];
        #pragma unroll
        for (int r = 0; r < N_REL; ++r) d[r] = wave_sum(x * rel[r * DD + lane]);
        float m = d[0];
        #pragma unroll
        for (int r = 1; r < N_REL; ++r) m = fmaxf(m, d[r]);
        float ssum = 0.f;
        #pragma unroll
        for (int r = 0; r < N_REL; ++r) { d[r] = expf(d[r] - m); ssum += d[r]; }
        const float inv = 1.f / ssum;
        float v = d[0];
        #pragma unroll
        for (int r = 1; r < N_REL; ++r) v = (lane == r) ? d[r] : v;
        if (lane < N_REL) smax[wid * N_REL + lane] = v * inv;  // same-wave LDS

        const int dg = e_deg[gw];
        const int j1 = e_end[gw];
        const int j0 = j1 - dg;
        float4 acc = make_float4(0.f, 0.f, 0.f, 0.f);
        for (int j = j0 + g; j < j1; j += 4) {
            const int2 pk = epack[j];                     // 8B, 1 line per group
            const int tl = pk.x & 0x1FFFF;
            const int et = pk.x >> 17;
            const float w = smax[wid * N_REL + et] * __int_as_float(pk.y);
            const float4 ev = *(const float4*)(e_src + (long long)tl * DD + s * 4);
            const float4 rv = *(const float4*)(rel + et * DD + s * 4);
            acc.x += ev.x * rv.x * w;
            acc.y += ev.y * rv.y * w;
            acc.z += ev.z * rv.z * w;
            acc.w += ev.w * rv.w * w;
        }
        // combine the 4 groups (lanes l, l+16, l+32, l+48 hold same element slot)
        acc.x += __shfl_xor(acc.x, 16, 64); acc.y += __shfl_xor(acc.y, 16, 64);
        acc.z += __shfl_xor(acc.z, 16, 64); acc.w += __shfl_xor(acc.w, 16, 64);
        acc.x += __shfl_xor(acc.x, 32, 64); acc.y += __shfl_xor(acc.y, 32, 64);
        acc.z += __shfl_xor(acc.z, 32, 64); acc.w += __shfl_xor(acc.w, 32, 64);
        float ss = acc.x * acc.x + acc.y * acc.y + acc.z * acc.z + acc.w * acc.w;
        #pragma unroll
        for (int off = 8; off; off >>= 1) ss += __shfl_xor(ss, off, 64);
        const float rinv = 1.f / fmaxf(sqrtf(ss), 1e-12f);
        if (g == 0) {
            const long long ro = (long long)gw * DD + s * 4;
            float4 y = make_float4(acc.x * rinv, acc.y * rinv, acc.z * rinv, acc.w * rinv);
            if (store_next) *(float4*)(e_next + ro) = y;
            float4 r0 = *(const float4*)(ent_res + ro);
            r0.x += y.x; r0.y += y.y; r0.z += y.z; r0.w += y.w;
            *(float4*)(ent_res + ro) = r0;
        }
    } else {
        const int gw = (blockIdx.x - ENT_BLKS) * 4 + wid;
        const long long o = (long long)gw * DD + lane;
        const float x = ub[o];
        // cluster softmax
        float d[N_CLS];
        #pragma unroll
        for (int c = 0; c < N_CLS; ++c) d[c] = wave_sum(x * uclsw[c * DD + lane]);
        float m = fmaxf(fmaxf(d[0], d[1]), fmaxf(d[2], d[3]));
        float ssum = 0.f;
        #pragma unroll
        for (int c = 0; c < N_CLS; ++c) { d[c] = expf(d[c] - m); ssum += d[c]; }
        const float inv = 1.f / ssum;
        float v = d[0];
        #pragma unroll
        for (int c = 1; c < N_CLS; ++c) v = (lane == c) ? d[c] : v;
        if (lane < N_CLS) smax[wid * N_REL + lane] = v * inv;

        float4 acc = make_float4(0.f, 0.f, 0.f, 0.f);
        {
            const int dg = i_deg[gw];
            const int j1 = i_end[gw];
            const int j0 = j1 - dg;
            for (int j = j0 + g; j < j1; j += 4) {
                const int2 pk = impack[j];
                const float w = __int_as_float(pk.y);
                const float4 ev = *(const float4*)(e_src + (long long)pk.x * DD + s * 4);
                acc.x += ev.x * w; acc.y += ev.y * w; acc.z += ev.z * w; acc.w += ev.w * w;
            }
        }
        float4 ac2 = make_float4(0.f, 0.f, 0.f, 0.f);
        {
            const int dg = c_deg[gw];
            const int j1 = c_end[gw];
            const int j0 = j1 - dg;
            for (int j = j0 + g; j < j1; j += 4) {
                const int2 pk = icpack[j];
                const int col = pk.x & 0x7FFF;
                const int cl  = pk.x >> 15;
                const float w = __int_as_float(pk.y) * smax[wid * N_REL + cl];
                const float4 ev = *(const float4*)(e_src + (long long)col * DD + s * 4);
                ac2.x += ev.x * w; ac2.y += ev.y * w; ac2.z += ev.z * w; ac2.w += ev.w * w;
            }
        }
        const float4 rs4 = *(const float4*)(rsum + s * 4);
        acc.x += ac2.x * rs4.x; acc.y += ac2.y * rs4.y;
        acc.z += ac2.z * rs4.z; acc.w += ac2.w * rs4.w;

        acc.x += __shfl_xor(acc.x, 16, 64); acc.y += __shfl_xor(acc.y, 16, 64);
        acc.z += __shfl_xor(acc.z, 16, 64); acc.w += __shfl_xor(acc.w, 16, 64);
        acc.x += __shfl_xor(acc.x, 32, 64); acc.y += __shfl_xor(acc.y, 32, 64);
        acc.z += __shfl_xor(acc.z, 32, 64); acc.w += __shfl_xor(acc.w, 32, 64);
        float ss = acc.x * acc.x + acc.y * acc.y + acc.z * acc.z + acc.w * acc.w;
        #pragma unroll
        for (int off = 8; off; off >>= 1) ss += __shfl_xor(ss, off, 64);
        const float rinv = 1.f / fmaxf(sqrtf(ss), 1e-12f);
        if (g == 0) {
            const long long ro = (long long)gw * DD + s * 4;
            float4 y = make_float4(acc.x * rinv, acc.y * rinv, acc.z * rinv, acc.w * rinv);
            *(float4*)(ub + ro) = y;                 // in-place (own row only)
            float4 r0 = *(const float4*)(usr_res + ro);
            r0.x += y.x; r0.y += y.y; r0.z += y.z; r0.w += y.w;
            *(float4*)(usr_res + ro) = r0;
        }
    }
}

// ---------- cor_loss ----------
__global__ void cor_kernel(const float* __restrict__ dwatt, float* __restrict__ out) {
    if (threadIdx.x != 0 || blockIdx.x != 0) return;
    float nt[4][16];
    #pragma unroll
    for (int i = 0; i < 4; ++i) {
        float ss = 0.f;
        #pragma unroll
        for (int j = 0; j < 16; ++j) { float v = dwatt[i * 16 + j]; ss += v * v; }
        float nrm = fmaxf(sqrtf(ss), 1e-12f);
        #pragma unroll
        for (int j = 0; j < 16; ++j) nt[i][j] = dwatt[i * 16 + j] / nrm;
    }
    float loss = 0.f;
    #pragma unroll
    for (int i = 0; i < 4; ++i) {
        float rowsum = 0.f, diag = 0.f;
        #pragma unroll
        for (int j = 0; j < 4; ++j) {
            float dd = 0.f;
            #pragma unroll
            for (int k = 0; k < 16; ++k) dd += nt[i][k] * nt[j][k];
            float s = expf(dd / TMP_);
            rowsum += s;
            if (i == j) diag = s;
        }
        loss -= logf(diag / rowsum);
    }
    out[0] = loss;
}

extern "C" void kernel_launch(void* const* d_in, const int* in_sizes, int n_in,
                              void* d_out, int out_size, void* d_ws, size_t ws_size,
                              hipStream_t stream) {
    const float* user_emb   = (const float*)d_in[0];
    const float* entity_emb = (const float*)d_in[1];
    const float* rel        = (const float*)d_in[3];
    const float* dwatt      = (const float*)d_in[4];
    const float* uclsw      = (const float*)d_in[5];
    const float* edge_imp   = (const float*)d_in[6];
    const float* im_vals    = (const float*)d_in[7];
    const float* icm_vals   = (const float*)d_in[8];
    const int*   edge_index = (const int*)d_in[9];
    const int*   edge_type  = (const int*)d_in[10];
    const int*   im_rows    = (const int*)d_in[11];
    const int*   im_cols    = (const int*)d_in[12];
    const int*   icm_cls    = (const int*)d_in[13];
    const int*   icm_rows   = (const int*)d_in[14];
    const int*   icm_cols   = (const int*)d_in[15];

    const int* head  = edge_index;
    const int* tailp = edge_index + N_EDGES;

    float* out     = (float*)d_out;
    float* ent_res = out;
    float* usr_res = out + (long long)N_ENT * DD;
    float* cor     = out + (long long)(N_ENT + N_USR) * DD;

    // ---- workspace layout (~68 MB) ----
    float* ws   = (float*)d_ws;
    float* eA   = ws;                                // 6.4M f
    float* ub   = eA + (size_t)N_ENT * DD;           // 3.2M f
    float* rsum = ub + (size_t)N_USR * DD;           // 64 f
    int2* epack  = (int2*)(rsum + DD);               // 1.5M int2
    int2* impack = epack + N_EDGES;                  // 1M int2
    int2* icpack = impack + NNZ_IM;                  // 1M int2
    int* ip    = (int*)(icpack + NNZ_ICM);
    int* e_deg = ip;  ip += N_ENT;
    int* e_cnt = ip;  ip += N_ENT;
    int* i_deg = ip;  ip += N_USR;
    int* i_cnt = ip;  ip += N_USR;
    int* c_deg = ip;  ip += N_USR;
    int* c_cnt = ip;  ip += N_USR;
    int* gc    = ip;  ip += 4;

    const int BLK = 256;

    // ---- build 3 packed CSRs (no scan: wave-aggregated segment allocator) ----
    hipMemsetAsync(e_deg, 0, sizeof(int) * N_ENT, stream);
    hipMemsetAsync(i_deg, 0, sizeof(int) * N_USR, stream);
    hipMemsetAsync(c_deg, 0, sizeof(int) * N_USR, stream);
    hipMemsetAsync(gc, 0, sizeof(int) * 4, stream);
    hist_kernel<<<(N_EDGES + BLK - 1) / BLK, BLK, 0, stream>>>(head, e_deg, N_EDGES);
    hist_kernel<<<(NNZ_IM + BLK - 1) / BLK, BLK, 0, stream>>>(im_rows, i_deg, NNZ_IM);
    hist_kernel<<<(NNZ_ICM + BLK - 1) / BLK, BLK, 0, stream>>>(icm_rows, c_deg, NNZ_ICM);
    assign_kernel<<<(N_ENT + BLK - 1) / BLK, BLK, 0, stream>>>(e_deg, e_cnt, gc + 0, N_ENT);
    assign_kernel<<<(N_USR + BLK - 1) / BLK, BLK, 0, stream>>>(i_deg, i_cnt, gc + 1, N_USR);
    assign_kernel<<<(N_USR + BLK - 1) / BLK, BLK, 0, stream>>>(c_deg, c_cnt, gc + 2, N_USR);
    scatter_edge_kernel<<<(N_EDGES + BLK - 1) / BLK, BLK, 0, stream>>>(
        head, tailp, edge_type, edge_imp, e_cnt, epack, N_EDGES);
    scatter_im_kernel<<<(NNZ_IM + BLK - 1) / BLK, BLK, 0, stream>>>(
        im_rows, im_cols, im_vals, i_cnt, impack, NNZ_IM);
    scatter_icm_kernel<<<(NNZ_ICM + BLK - 1) / BLK, BLK, 0, stream>>>(
        icm_rows, icm_cols, icm_cls, icm_vals, c_cnt, icpack, NNZ_ICM);
    // after scatter: cnt[i] == segment end; start = end - deg

    // ---- init state ----
    rsum_kernel<<<1, 64, 0, stream>>>(rel, rsum);
    hipMemcpyAsync(ub, user_emb, sizeof(float) * N_USR * DD, hipMemcpyDeviceToDevice, stream);
    hipMemcpyAsync(ent_res, entity_emb, sizeof(float) * N_ENT * DD, hipMemcpyDeviceToDevice, stream);
    hipMemcpyAsync(usr_res, user_emb, sizeof(float) * N_USR * DD, hipMemcpyDeviceToDevice, stream);

    // ---- hop 0: read entity_emb, write eA ----
    hop_kernel<<<ENT_BLKS + USR_BLKS, BLK, 0, stream>>>(
        entity_emb, eA, ub, rel, uclsw, rsum,
        e_deg, e_cnt, epack, i_deg, i_cnt, impack, c_deg, c_cnt, icpack,
        ent_res, usr_res, 1);
    // ---- hop 1: read eA, e_next store disabled (dead) ----
    hop_kernel<<<ENT_BLKS + USR_BLKS, BLK, 0, stream>>>(
        eA, eA, ub, rel, uclsw, rsum,
        e_deg, e_cnt, epack, i_deg, i_cnt, impack, c_deg, c_cnt, icpack,
        ent_res, usr_res, 0);

    cor_kernel<<<1, 1, 0, stream>>>(dwatt, cor);
}

// Round 4
// 875.508 us; speedup vs baseline: 7.3158x; 1.0781x over previous
//
#include <hip/hip_runtime.h>
#include <math.h>

#define N_ENT   100000
#define N_USR   50000
#define DD      64
#define N_REL   16
#define N_CLS   4
#define N_EDGES 1500000
#define NNZ_IM  1000000
#define NNZ_ICM 1000000
#define TMP_    0.2f
#define ENT_BLKS (N_ENT / 4)
#define USR_BLKS (N_USR / 4)
#define TOT3    (N_EDGES + NNZ_IM + NNZ_ICM)
// assign-kernel region padding to wave multiples
#define R0 100032   // ceil(N_ENT/64)*64
#define R1 50048    // ceil(N_USR/64)*64
#define ASSIGN_THREADS (R0 + R1 + R1)
#define ASSIGN_BLKS ((ASSIGN_THREADS + 255) / 256)

// ---------- fused histogram: all 3 index arrays, one combined deg[] ----------
__global__ void build_hist(const int* __restrict__ head, const int* __restrict__ im_rows,
                           const int* __restrict__ icm_rows, int* __restrict__ deg) {
    int i = blockIdx.x * blockDim.x + threadIdx.x;
    if (i < N_EDGES) atomicAdd(&deg[head[i]], 1);
    else if (i < N_EDGES + NNZ_IM) atomicAdd(&deg[N_ENT + im_rows[i - N_EDGES]], 1);
    else if (i < TOT3) atomicAdd(&deg[N_ENT + N_USR + icm_rows[i - N_EDGES - NNZ_IM]], 1);
}

// ---------- fused assign (wave-aggregated segment allocator) + rsum + cor ----------
__global__ void build_assign(const int* __restrict__ deg, int* __restrict__ cnt, int* __restrict__ gc,
                             const float* __restrict__ rel, float* __restrict__ rsum,
                             const float* __restrict__ dwatt, float* __restrict__ cor) {
    if (blockIdx.x >= ASSIGN_BLKS) {
        if (blockIdx.x == ASSIGN_BLKS) {            // rsum = relation_emb.sum(0)
            if (threadIdx.x < DD) {
                float sm = 0.f;
                #pragma unroll
                for (int r = 0; r < N_REL; ++r) sm += rel[r * DD + threadIdx.x];
                rsum[threadIdx.x] = sm;
            }
        } else if (threadIdx.x == 0) {              // cor_loss (4x16, trivial)
            float nt[4][16];
            #pragma unroll
            for (int i = 0; i < 4; ++i) {
                float ss = 0.f;
                #pragma unroll
                for (int j = 0; j < 16; ++j) { float v = dwatt[i * 16 + j]; ss += v * v; }
                float nrm = fmaxf(sqrtf(ss), 1e-12f);
                #pragma unroll
                for (int j = 0; j < 16; ++j) nt[i][j] = dwatt[i * 16 + j] / nrm;
            }
            float loss = 0.f;
            #pragma unroll
            for (int i = 0; i < 4; ++i) {
                float rowsum = 0.f, diag = 0.f;
                #pragma unroll
                for (int j = 0; j < 4; ++j) {
                    float dd = 0.f;
                    #pragma unroll
                    for (int k = 0; k < 16; ++k) dd += nt[i][k] * nt[j][k];
                    float sx = expf(dd / TMP_);
                    rowsum += sx;
                    if (i == j) diag = sx;
                }
                loss -= logf(diag / rowsum);
            }
            cor[0] = loss;
        }
        return;
    }
    int gid = blockIdx.x * blockDim.x + threadIdx.x;
    int lane = threadIdx.x & 63;
    int region, idx, n, base;
    if (gid < R0)           { region = 0; idx = gid;           n = N_ENT; base = 0; }
    else if (gid < R0 + R1) { region = 1; idx = gid - R0;      n = N_USR; base = N_ENT; }
    else                    { region = 2; idx = gid - R0 - R1; n = N_USR; base = N_ENT + N_USR; }
    int d = (idx < n) ? deg[base + idx] : 0;
    int incl = d;
    #pragma unroll
    for (int off = 1; off < 64; off <<= 1) {
        int t = __shfl_up(incl, off, 64);
        if (lane >= off) incl += t;
    }
    int b = 0;
    if (lane == 63) b = atomicAdd(&gc[region], incl);
    b = __shfl(b, 63, 64);
    if (idx < n) cnt[base + idx] = b + incl - d;
}

// ---------- fused scatter: build all 3 packed CSRs ----------
__global__ void build_scatter(const int* __restrict__ head, const int* __restrict__ tailp,
                              const int* __restrict__ etype, const float* __restrict__ imp,
                              const int* __restrict__ im_rows, const int* __restrict__ im_cols,
                              const float* __restrict__ im_vals,
                              const int* __restrict__ icm_rows, const int* __restrict__ icm_cols,
                              const int* __restrict__ icm_cls, const float* __restrict__ icm_vals,
                              int* __restrict__ cnt,
                              int2* __restrict__ epack, int2* __restrict__ impack,
                              int2* __restrict__ icpack) {
    int i = blockIdx.x * blockDim.x + threadIdx.x;
    if (i < N_EDGES) {
        int p = atomicAdd(&cnt[head[i]], 1);
        epack[p] = make_int2(tailp[i] | (etype[i] << 17), __float_as_int(imp[i]));
    } else if (i < N_EDGES + NNZ_IM) {
        int k = i - N_EDGES;
        int p = atomicAdd(&cnt[N_ENT + im_rows[k]], 1);
        impack[p] = make_int2(im_cols[k], __float_as_int(im_vals[k]));
    } else if (i < TOT3) {
        int k = i - N_EDGES - NNZ_IM;
        int p = atomicAdd(&cnt[N_ENT + N_USR + icm_rows[k]], 1);
        icpack[p] = make_int2(icm_cols[k] | (icm_cls[k] << 15), __float_as_int(icm_vals[k]));
    }
}

// ---------- fused per-hop kernel ----------
// entity blocks then user blocks; 16-lane groups, float4/lane in the gather.
// Softmaxes use transposed layout: reduce-in-register first, then 2-4 shuffle
// stages (instead of 16 serial 6-stage wave_sums -> DS-latency chain).
__global__ void __launch_bounds__(256) hop_kernel(
    const float* __restrict__ e_src, float* __restrict__ e_next,
    const float* __restrict__ u_src, float* __restrict__ u_dst,
    const float* __restrict__ rel, const float* __restrict__ uclsw,
    const float* __restrict__ rsum,
    const int* __restrict__ deg, const int* __restrict__ endp,
    const int2* __restrict__ epack, const int2* __restrict__ impack,
    const int2* __restrict__ icpack,
    const float* __restrict__ e_init, const float* __restrict__ u_init,
    float* __restrict__ ent_res, float* __restrict__ usr_res,
    int first, int store_next)
{
    __shared__ float smax[4 * N_REL];
    const int lane = threadIdx.x & 63;
    const int wid  = threadIdx.x >> 6;
    const int g = lane >> 4;        // 0..3  (slot group)
    const int s = lane & 15;        // 0..15 (element / relation slot)

    if (blockIdx.x < ENT_BLKS) {
        const int gw = blockIdx.x * 4 + wid;
        // --- relation softmax, transposed: lane (g,s) = relation s, elems [16g,16g+16) ---
        {
            const float* erow = e_src + (size_t)gw * DD + g * 16;
            const float* rrow = rel + s * DD + g * 16;
            float dp = 0.f;
            #pragma unroll
            for (int q = 0; q < 4; ++q) {
                float4 a = *(const float4*)(erow + q * 4);
                float4 b = *(const float4*)(rrow + q * 4);
                dp += a.x * b.x + a.y * b.y + a.z * b.z + a.w * b.w;
            }
            float df = dp + __shfl_xor(dp, 16, 64);
            df += __shfl_xor(df, 32, 64);                      // full dot for relation s
            float mm = df;
            #pragma unroll
            for (int off = 1; off < 16; off <<= 1) mm = fmaxf(mm, __shfl_xor(mm, off, 64));
            float p = __expf(df - mm);
            float ps = p;
            #pragma unroll
            for (int off = 1; off < 16; off <<= 1) ps += __shfl_xor(ps, off, 64);
            if (g == 0) smax[wid * N_REL + s] = p / ps;        // same-wave LDS, no barrier
        }
        // --- CSR gather: 4 slots in flight per wave ---
        const int dg = deg[gw];
        const int j1 = endp[gw];
        const int j0 = j1 - dg;
        float4 acc = make_float4(0.f, 0.f, 0.f, 0.f);
        for (int j = j0 + g; j < j1; j += 4) {
            const int2 pk = epack[j];
            const int tl = pk.x & 0x1FFFF;
            const int et = pk.x >> 17;
            const float w = smax[wid * N_REL + et] * __int_as_float(pk.y);
            const float4 ev = *(const float4*)(e_src + (size_t)tl * DD + s * 4);
            const float4 rv = *(const float4*)(rel + et * DD + s * 4);
            acc.x += ev.x * rv.x * w;
            acc.y += ev.y * rv.y * w;
            acc.z += ev.z * rv.z * w;
            acc.w += ev.w * rv.w * w;
        }
        acc.x += __shfl_xor(acc.x, 16, 64); acc.y += __shfl_xor(acc.y, 16, 64);
        acc.z += __shfl_xor(acc.z, 16, 64); acc.w += __shfl_xor(acc.w, 16, 64);
        acc.x += __shfl_xor(acc.x, 32, 64); acc.y += __shfl_xor(acc.y, 32, 64);
        acc.z += __shfl_xor(acc.z, 32, 64); acc.w += __shfl_xor(acc.w, 32, 64);
        float ss = acc.x * acc.x + acc.y * acc.y + acc.z * acc.z + acc.w * acc.w;
        #pragma unroll
        for (int off = 1; off < 16; off <<= 1) ss += __shfl_xor(ss, off, 64);
        const float rinv = 1.f / fmaxf(sqrtf(ss), 1e-12f);
        if (g == 0) {
            const size_t ro = (size_t)gw * DD + s * 4;
            float4 y = make_float4(acc.x * rinv, acc.y * rinv, acc.z * rinv, acc.w * rinv);
            if (store_next) *(float4*)(e_next + ro) = y;
            float4 r0 = first ? *(const float4*)(e_init + ro)
                              : *(const float4*)(ent_res + ro);
            r0.x += y.x; r0.y += y.y; r0.z += y.z; r0.w += y.w;
            *(float4*)(ent_res + ro) = r0;
        }
    } else {
        const int gw = (blockIdx.x - ENT_BLKS) * 4 + wid;
        // --- cluster softmax, transposed: lane = chunk*4 + c ---
        {
            const int c = lane & 3, chunk = lane >> 2;
            float4 a = *(const float4*)(u_src + (size_t)gw * DD + chunk * 4);
            float4 b = *(const float4*)(uclsw + c * DD + chunk * 4);
            float dp = a.x * b.x + a.y * b.y + a.z * b.z + a.w * b.w;
            #pragma unroll
            for (int off = 4; off < 64; off <<= 1) dp += __shfl_xor(dp, off, 64);
            float mm = fmaxf(dp, __shfl_xor(dp, 1, 64));
            mm = fmaxf(mm, __shfl_xor(mm, 2, 64));
            float p = __expf(dp - mm);
            float ps = p + __shfl_xor(p, 1, 64);
            ps += __shfl_xor(ps, 2, 64);
            if (lane < N_CLS) smax[wid * N_REL + lane] = p / ps;  // lanes 0-3: chunk==0, c==lane
        }
        float4 acc = make_float4(0.f, 0.f, 0.f, 0.f);
        {
            const int dg = deg[N_ENT + gw];
            const int j1 = endp[N_ENT + gw];
            const int j0 = j1 - dg;
            for (int j = j0 + g; j < j1; j += 4) {
                const int2 pk = impack[j];
                const float w = __int_as_float(pk.y);
                const float4 ev = *(const float4*)(e_src + (size_t)pk.x * DD + s * 4);
                acc.x += ev.x * w; acc.y += ev.y * w; acc.z += ev.z * w; acc.w += ev.w * w;
            }
        }
        float4 ac2 = make_float4(0.f, 0.f, 0.f, 0.f);
        {
            const int dg = deg[N_ENT + N_USR + gw];
            const int j1 = endp[N_ENT + N_USR + gw];
            const int j0 = j1 - dg;
            for (int j = j0 + g; j < j1; j += 4) {
                const int2 pk = icpack[j];
                const int col = pk.x & 0x7FFF;
                const int cl  = pk.x >> 15;
                const float w = __int_as_float(pk.y) * smax[wid * N_REL + cl];
                const float4 ev = *(const float4*)(e_src + (size_t)col * DD + s * 4);
                ac2.x += ev.x * w; ac2.y += ev.y * w; ac2.z += ev.z * w; ac2.w += ev.w * w;
            }
        }
        const float4 rs4 = *(const float4*)(rsum + s * 4);
        acc.x += ac2.x * rs4.x; acc.y += ac2.y * rs4.y;
        acc.z += ac2.z * rs4.z; acc.w += ac2.w * rs4.w;

        acc.x += __shfl_xor(acc.x, 16, 64); acc.y += __shfl_xor(acc.y, 16, 64);
        acc.z += __shfl_xor(acc.z, 16, 64); acc.w += __shfl_xor(acc.w, 16, 64);
        acc.x += __shfl_xor(acc.x, 32, 64); acc.y += __shfl_xor(acc.y, 32, 64);
        acc.z += __shfl_xor(acc.z, 32, 64); acc.w += __shfl_xor(acc.w, 32, 64);
        float ss = acc.x * acc.x + acc.y * acc.y + acc.z * acc.z + acc.w * acc.w;
        #pragma unroll
        for (int off = 1; off < 16; off <<= 1) ss += __shfl_xor(ss, off, 64);
        const float rinv = 1.f / fmaxf(sqrtf(ss), 1e-12f);
        if (g == 0) {
            const size_t ro = (size_t)gw * DD + s * 4;
            float4 y = make_float4(acc.x * rinv, acc.y * rinv, acc.z * rinv, acc.w * rinv);
            *(float4*)(u_dst + ro) = y;
            float4 r0 = first ? *(const float4*)(u_init + ro)
                              : *(const float4*)(usr_res + ro);
            r0.x += y.x; r0.y += y.y; r0.z += y.z; r0.w += y.w;
            *(float4*)(usr_res + ro) = r0;
        }
    }
}

extern "C" void kernel_launch(void* const* d_in, const int* in_sizes, int n_in,
                              void* d_out, int out_size, void* d_ws, size_t ws_size,
                              hipStream_t stream) {
    const float* user_emb   = (const float*)d_in[0];
    const float* entity_emb = (const float*)d_in[1];
    const float* rel        = (const float*)d_in[3];
    const float* dwatt      = (const float*)d_in[4];
    const float* uclsw      = (const float*)d_in[5];
    const float* edge_imp   = (const float*)d_in[6];
    const float* im_vals    = (const float*)d_in[7];
    const float* icm_vals   = (const float*)d_in[8];
    const int*   edge_index = (const int*)d_in[9];
    const int*   edge_type  = (const int*)d_in[10];
    const int*   im_rows    = (const int*)d_in[11];
    const int*   im_cols    = (const int*)d_in[12];
    const int*   icm_cls    = (const int*)d_in[13];
    const int*   icm_rows   = (const int*)d_in[14];
    const int*   icm_cols   = (const int*)d_in[15];

    const int* head  = edge_index;
    const int* tailp = edge_index + N_EDGES;

    float* out     = (float*)d_out;
    float* ent_res = out;
    float* usr_res = out + (size_t)N_ENT * DD;
    float* cor     = out + (size_t)(N_ENT + N_USR) * DD;

    // ---- workspace layout (~68 MB) ----
    float* ws   = (float*)d_ws;
    float* eA   = ws;                                // 6.4M f
    float* ub   = eA + (size_t)N_ENT * DD;           // 3.2M f
    float* rsum = ub + (size_t)N_USR * DD;           // 64 f
    int2* epack  = (int2*)(rsum + DD);               // 1.5M int2
    int2* impack = epack + N_EDGES;                  // 1M int2
    int2* icpack = impack + NNZ_IM;                  // 1M int2
    int* deg = (int*)(icpack + NNZ_ICM);             // N_ENT + 2*N_USR
    int* gc  = deg + N_ENT + 2 * N_USR;              // 4  (contiguous with deg -> one memset)
    int* cnt = gc + 4;                               // N_ENT + 2*N_USR

    const int BLK = 256;
    const int NB3 = (TOT3 + BLK - 1) / BLK;

    // ---- build: 1 memset + 3 fused kernels (rsum & cor ride on build_assign) ----
    hipMemsetAsync(deg, 0, sizeof(int) * (N_ENT + 2 * N_USR + 4), stream);
    build_hist<<<NB3, BLK, 0, stream>>>(head, im_rows, icm_rows, deg);
    build_assign<<<ASSIGN_BLKS + 2, BLK, 0, stream>>>(deg, cnt, gc, rel, rsum, dwatt, cor);
    build_scatter<<<NB3, BLK, 0, stream>>>(head, tailp, edge_type, edge_imp,
                                           im_rows, im_cols, im_vals,
                                           icm_rows, icm_cols, icm_cls, icm_vals,
                                           cnt, epack, impack, icpack);
    // after scatter: cnt[i] == segment end; start = end - deg

    // ---- hop 0: read inputs directly, init residuals in epilogue ----
    hop_kernel<<<ENT_BLKS + USR_BLKS, BLK, 0, stream>>>(
        entity_emb, eA, user_emb, ub, rel, uclsw, rsum,
        deg, cnt, epack, impack, icpack,
        entity_emb, user_emb, ent_res, usr_res, 1, 1);
    // ---- hop 1: read eA/ub; e_next store dead ----
    hop_kernel<<<ENT_BLKS + USR_BLKS, BLK, 0, stream>>>(
        eA, eA, ub, ub, rel, uclsw, rsum,
        deg, cnt, epack, impack, icpack,
        entity_emb, user_emb, ent_res, usr_res, 0, 0);
}